// Round 2
// 16692.087 us; speedup vs baseline: 1.2432x; 1.2432x over previous
//
#include <hip/hip_runtime.h>

#define VOCAB 32000
#define EMBED 1024
#define HID   1024
#define BATCH 64
#define SEQ   512
#define R4    4096   // 4*HID gate rows (i,f,g,o)

typedef float floatx4 __attribute__((ext_vector_type(4)));
typedef unsigned int uintx2 __attribute__((ext_vector_type(2)));
typedef short bf16x8  __attribute__((ext_vector_type(8)));   // 8 bf16 = 4 VGPRs

// fp32 -> bf16 round-to-nearest-even
static __device__ __forceinline__ unsigned short f2bf(float x) {
    unsigned int u = __float_as_uint(x);
    u = (u + 0x7FFFu + ((u >> 16) & 1u)) >> 16;
    return (unsigned short)u;
}

// load 8 contiguous fp32, convert to bf16x8 fragment
static __device__ __forceinline__ bf16x8 cvt8(const float* p) {
    float4 a = ((const float4*)p)[0];
    float4 b = ((const float4*)p)[1];
    bf16x8 r;
    r[0] = (short)f2bf(a.x); r[1] = (short)f2bf(a.y);
    r[2] = (short)f2bf(a.z); r[3] = (short)f2bf(a.w);
    r[4] = (short)f2bf(b.x); r[5] = (short)f2bf(b.y);
    r[6] = (short)f2bf(b.z); r[7] = (short)f2bf(b.w);
    return r;
}

// ---------------------------------------------------------------------------
// Phase A: gx[s][r][b] = emb[seq[b][s]] . W_ih[r] + b_ih[r] + b_hh[r]  (fp32)
// (unchanged; zeroes the phase-B barrier counter)
// ---------------------------------------------------------------------------
__global__ __launch_bounds__(256) void gates_x_mfma(
    const float* __restrict__ emb, const float* __restrict__ Wih,
    const float* __restrict__ bih, const float* __restrict__ bhh,
    const int* __restrict__ seq, float* __restrict__ gx,
    unsigned int* cnt)
{
    if (blockIdx.x == 0 && blockIdx.y == 0 && threadIdx.x == 0) *cnt = 0u;

    __shared__ unsigned short Als[64 * 136];   // 64 rows x 128 k bf16, stride 136
    __shared__ int tok[64];

    const int tid = threadIdx.x;
    const int s   = blockIdx.x;
    const int r0  = blockIdx.y * 128;

    if (tid < 64) tok[tid] = seq[tid * SEQ + s];
    __syncthreads();

    const int w   = tid >> 6;
    const int l   = tid & 63;
    const int l16 = l & 15;
    const int kq  = l >> 4;

    const float* wrow0 = Wih + (size_t)(r0 + 32 * w + l16) * EMBED;
    const float* wrow1 = wrow0 + 16 * EMBED;

    floatx4 acc[4][2];
#pragma unroll
    for (int mt = 0; mt < 4; ++mt)
#pragma unroll
        for (int nt = 0; nt < 2; ++nt)
            acc[mt][nt] = (floatx4){0.f, 0.f, 0.f, 0.f};

    const int arow  = tid >> 2;
    const int apart = tid & 3;
    const float* asrc_base = emb + (size_t)tok[arow] * EMBED + apart * 32;
    unsigned short* adst = Als + arow * 136 + apart * 32;

    for (int kb = 0; kb < EMBED; kb += 128) {
        const float* asrc = asrc_base + kb;
#pragma unroll
        for (int j = 0; j < 4; ++j)
            *(bf16x8*)(adst + j * 8) = cvt8(asrc + j * 8);
        __syncthreads();

#pragma unroll
        for (int kc = 0; kc < 4; ++kc) {
            const int ko = kb + kc * 32 + kq * 8;
            const bf16x8 b0 = cvt8(wrow0 + ko);
            const bf16x8 b1 = cvt8(wrow1 + ko);
#pragma unroll
            for (int mt = 0; mt < 4; ++mt) {
                const bf16x8 af = *(const bf16x8*)(Als + (mt * 16 + l16) * 136 + kc * 32 + kq * 8);
                acc[mt][0] = __builtin_amdgcn_mfma_f32_16x16x32_bf16(af, b0, acc[mt][0], 0, 0, 0);
                acc[mt][1] = __builtin_amdgcn_mfma_f32_16x16x32_bf16(af, b1, acc[mt][1], 0, 0, 0);
            }
        }
        __syncthreads();
    }

    const int rA = r0 + 32 * w + l16;
    const float bv0 = bih[rA] + bhh[rA];
    const float bv1 = bih[rA + 16] + bhh[rA + 16];
    float* gxs = gx + (size_t)s * (R4 * BATCH);
#pragma unroll
    for (int nt = 0; nt < 2; ++nt) {
        const float bv = nt ? bv1 : bv0;
        const int r = rA + 16 * nt;
#pragma unroll
        for (int mt = 0; mt < 4; ++mt) {
            float4 v;
            v.x = acc[mt][nt][0] + bv;
            v.y = acc[mt][nt][1] + bv;
            v.z = acc[mt][nt][2] + bv;
            v.w = acc[mt][nt][3] + bv;
            *(float4*)(gxs + (size_t)r * BATCH + mt * 16 + kq * 4) = v;
        }
    }
}

// ---------------------------------------------------------------------------
// Phase B: persistent LSTM, 256 blocks x 256 thr (cooperative launch for
// co-residency only). Custom split arrive/wait barrier replaces cg grid.sync:
//   wave0: coalesced nt stores of h (8B) + out (16B)  -> fence(release,agent)
//   tid0 : relaxed agent atomicAdd(cnt) ; all: prefetch gx(s+1) during poll
//   tid0 : poll cnt with relaxed agent atomic loads (+s_sleep)
//   sync ; fence(acquire,agent) on every wave
// MFMA reduction split into 2 independent accumulator chains.
// ---------------------------------------------------------------------------
__global__ __launch_bounds__(256) void lstm_mfma(
    const float* __restrict__ gx, const float* __restrict__ Whh,
    unsigned short* __restrict__ h0buf, unsigned short* __restrict__ h1buf,
    unsigned int* cnt, float* __restrict__ out)
{
    __shared__ unsigned short Wlds[16 * 1032];  // 16 rows x 1024 bf16, stride 1032
    __shared__ float Slds[16 * 66];             // D staging [m=16][b=64] fp32
    __shared__ __align__(16) unsigned short Hst[64 * 4];  // h stage [b][ul] bf16
    __shared__ __align__(16) float          Ost[64 * 4];  // out stage [b][ul] fp32

    const int tid = threadIdx.x;
    const int w   = tid >> 6;
    const int l   = tid & 63;
    const int l16 = l & 15;
    const int kq  = l >> 4;
    const int u0  = blockIdx.x * 4;

    // one-time: stage this block's 16 W_hh rows to LDS as bf16
    {
        const int m = tid >> 4;       // 0..15 : m = gate*4 + ulocal
        const int p = tid & 15;
        const int gate = m >> 2, ulm = m & 3;
        const float* src = Whh + (size_t)(gate * HID + u0 + ulm) * HID + p * 64;
        unsigned short* dst = Wlds + m * 1032 + p * 64;
#pragma unroll
        for (int j = 0; j < 8; ++j)
            *(bf16x8*)(dst + j * 8) = cvt8(src + j * 8);
    }

    const int ul = w;
    const int b  = l;
    const int u  = u0 + ul;

    float c = 0.f, hval = 0.f;

    // ---- prologue: zero h0 slice, release, arrive, prefetch gx(0), wait ----
    if (w == 0) {
        uintx2 z; z.x = 0u; z.y = 0u;
        __builtin_nontemporal_store(z, (uintx2*)(h0buf + (size_t)tid * HID + u0));
        __builtin_amdgcn_fence(__ATOMIC_RELEASE, "agent");
    }
    __syncthreads();   // also orders Wlds staging before first use
    unsigned int tgt = 256u;
    if (tid == 0)
        __hip_atomic_fetch_add(cnt, 1u, __ATOMIC_RELAXED, __HIP_MEMORY_SCOPE_AGENT);

    float gxi = gx[(size_t)(0 * HID + u) * BATCH + b];
    float gxf = gx[(size_t)(1 * HID + u) * BATCH + b];
    float gxg = gx[(size_t)(2 * HID + u) * BATCH + b];
    float gxo = gx[(size_t)(3 * HID + u) * BATCH + b];

    if (tid == 0) {
        while (__hip_atomic_load(cnt, __ATOMIC_RELAXED, __HIP_MEMORY_SCOPE_AGENT) < tgt)
            __builtin_amdgcn_s_sleep(1);
    }
    __syncthreads();
    __builtin_amdgcn_fence(__ATOMIC_ACQUIRE, "agent");

    const unsigned short* wbase = Wlds + l16 * 1032 + kq * 8;   // A-frag: m=l16

    for (int s = 0; s < SEQ; ++s) {
        const unsigned short* hb = (s & 1) ? h1buf : h0buf;
        unsigned short*       hn = (s & 1) ? h0buf : h1buf;

        // B-frag: n = batch 16w+l16, k contiguous -> 16B loads
        const unsigned short* hbase = hb + (size_t)(16 * w + l16) * HID + kq * 8;

        floatx4 acc0 = (floatx4){0.f, 0.f, 0.f, 0.f};
        floatx4 acc1 = (floatx4){0.f, 0.f, 0.f, 0.f};
#pragma unroll
        for (int kc = 0; kc < 32; kc += 2) {
            const bf16x8 bf0 = *(const bf16x8*)(hbase + kc * 32);
            const bf16x8 af0 = *(const bf16x8*)(wbase + kc * 32);
            const bf16x8 bf1 = *(const bf16x8*)(hbase + (kc + 1) * 32);
            const bf16x8 af1 = *(const bf16x8*)(wbase + (kc + 1) * 32);
            acc0 = __builtin_amdgcn_mfma_f32_16x16x32_bf16(af0, bf0, acc0, 0, 0, 0);
            acc1 = __builtin_amdgcn_mfma_f32_16x16x32_bf16(af1, bf1, acc1, 0, 0, 0);
        }
        const floatx4 acc = acc0 + acc1;

        // D: m = kq*4+reg, n = 16w+l16
#pragma unroll
        for (int r = 0; r < 4; ++r)
            Slds[(kq * 4 + r) * 66 + 16 * w + l16] = acc[r];
        __syncthreads();                       // sync_a

        const float pi = Slds[(0 * 4 + ul) * 66 + b] + gxi;
        const float pf = Slds[(1 * 4 + ul) * 66 + b] + gxf;
        const float pg = Slds[(2 * 4 + ul) * 66 + b] + gxg;
        const float po = Slds[(3 * 4 + ul) * 66 + b] + gxo;

        const float ig = 1.f / (1.f + __expf(-pi));
        const float fg = 1.f / (1.f + __expf(-pf));
        const float gg = 2.f / (1.f + __expf(-2.f * pg)) - 1.f;   // tanh
        const float og = 1.f / (1.f + __expf(-po));
        c = fg * c + ig * gg;
        const float th = 2.f / (1.f + __expf(-2.f * c)) - 1.f;
        hval = og * th;

        Hst[b * 4 + ul] = f2bf(hval);
        Ost[b * 4 + ul] = hval;
        __syncthreads();                       // sync_b

        // wave0: coalesced nt stores of h (8B/row) and out (16B/row), then
        // release so tid0's (wave0) arrive is ordered after them.
        if (w == 0) {
            const uintx2  hv = *(const uintx2*)(Hst + tid * 4);
            const floatx4 ov = *(const floatx4*)(Ost + tid * 4);
            __builtin_nontemporal_store(hv, (uintx2*)(hn + (size_t)tid * HID + u0));
            __builtin_nontemporal_store(ov, (floatx4*)(out + ((size_t)tid * SEQ + s) * HID + u0));
            __builtin_amdgcn_fence(__ATOMIC_RELEASE, "agent");
        }
        // arrive (sync_b already ordered all waves' reads of hb this step)
        if (tid == 0)
            __hip_atomic_fetch_add(cnt, 1u, __ATOMIC_RELAXED, __HIP_MEMORY_SCOPE_AGENT);
        tgt += 256u;

        // prefetch next step's gx during the poll window
        {
            const int sn = (s + 1 < SEQ) ? s + 1 : s;
            const float* gxs = gx + (size_t)sn * (R4 * BATCH);
            gxi = gxs[(size_t)(0 * HID + u) * BATCH + b];
            gxf = gxs[(size_t)(1 * HID + u) * BATCH + b];
            gxg = gxs[(size_t)(2 * HID + u) * BATCH + b];
            gxo = gxs[(size_t)(3 * HID + u) * BATCH + b];
        }

        if (tid == 0) {
            while (__hip_atomic_load(cnt, __ATOMIC_RELAXED, __HIP_MEMORY_SCOPE_AGENT) < tgt)
                __builtin_amdgcn_s_sleep(1);
        }
        __syncthreads();                       // sync2: holds all waves on poll
        __builtin_amdgcn_fence(__ATOMIC_ACQUIRE, "agent");
    }

    float* hlast = out + (size_t)BATCH * SEQ * HID;
    float* clast = hlast + (size_t)BATCH * HID;
    hlast[(size_t)b * HID + u] = hval;
    clast[(size_t)b * HID + u] = c;
}

// ---------------------------------------------------------------------------
extern "C" void kernel_launch(void* const* d_in, const int* in_sizes, int n_in,
                              void* d_out, int out_size, void* d_ws, size_t ws_size,
                              hipStream_t stream)
{
    const float* emb = (const float*)d_in[0];
    const float* Wih = (const float*)d_in[1];
    const float* Whh = (const float*)d_in[2];
    const float* bih = (const float*)d_in[3];
    const float* bhh = (const float*)d_in[4];
    const int*   seq = (const int*)d_in[5];
    float* out = (float*)d_out;

    // ws: gx fp32 [512][4096][64] + 2 bf16 h buffers + barrier counter
    float* gx = (float*)d_ws;
    unsigned short* h0 = (unsigned short*)(gx + (size_t)SEQ * R4 * BATCH);
    unsigned short* h1 = h0 + (size_t)BATCH * HID;

    const size_t needed = (size_t)SEQ * R4 * BATCH * 4 + (size_t)2 * BATCH * HID * 2;
    unsigned int* cnt;
    if (ws_size >= needed + 4) {
        cnt = (unsigned int*)(h1 + (size_t)BATCH * HID);
    } else {
        // fallback: last float of c_last (only overwritten after all barriers)
        cnt = (unsigned int*)((float*)d_out + (size_t)BATCH * SEQ * HID
                              + 2 * (size_t)BATCH * HID - 1);
    }

    dim3 gA(512, 32);
    gates_x_mfma<<<gA, 256, 0, stream>>>(emb, Wih, bih, bhh, seq, gx, cnt);

    void* args[] = { (void*)&gx, (void*)&Whh, (void*)&h0, (void*)&h1,
                     (void*)&cnt, (void*)&out };
    (void)hipLaunchCooperativeKernel((void*)lstm_mfma, dim3(256), dim3(256), args, 0, stream);
}

// Round 3
// 13847.528 us; speedup vs baseline: 1.4986x; 1.2054x over previous
//
#include <hip/hip_runtime.h>

#define VOCAB 32000
#define EMBED 1024
#define HID   1024
#define BATCH 64
#define SEQ   512
#define R4    4096   // 4*HID gate rows (i,f,g,o)
#define NBLK  256    // phase-B grid size

typedef float floatx4 __attribute__((ext_vector_type(4)));
typedef unsigned int uintx2 __attribute__((ext_vector_type(2)));
typedef short bf16x8  __attribute__((ext_vector_type(8)));   // 8 bf16 = 4 VGPRs

// fp32 -> bf16 round-to-nearest-even
static __device__ __forceinline__ unsigned short f2bf(float x) {
    unsigned int u = __float_as_uint(x);
    u = (u + 0x7FFFu + ((u >> 16) & 1u)) >> 16;
    return (unsigned short)u;
}

// load 8 contiguous fp32, convert to bf16x8 fragment
static __device__ __forceinline__ bf16x8 cvt8(const float* p) {
    float4 a = ((const float4*)p)[0];
    float4 b = ((const float4*)p)[1];
    bf16x8 r;
    r[0] = (short)f2bf(a.x); r[1] = (short)f2bf(a.y);
    r[2] = (short)f2bf(a.z); r[3] = (short)f2bf(a.w);
    r[4] = (short)f2bf(b.x); r[5] = (short)f2bf(b.y);
    r[6] = (short)f2bf(b.z); r[7] = (short)f2bf(b.w);
    return r;
}

// ---------------------------------------------------------------------------
// Phase A: gx[s][r][b] = emb[seq[b][s]] . W_ih[r] + b_ih[r] + b_hh[r]  (fp32)
// (unchanged; zeroes the phase-B barrier flag array each replay)
// ---------------------------------------------------------------------------
__global__ __launch_bounds__(256) void gates_x_mfma(
    const float* __restrict__ emb, const float* __restrict__ Wih,
    const float* __restrict__ bih, const float* __restrict__ bhh,
    const int* __restrict__ seq, float* __restrict__ gx,
    unsigned int* flags)
{
    if (blockIdx.x == 0 && blockIdx.y == 0) flags[threadIdx.x] = 0u;

    __shared__ unsigned short Als[64 * 136];   // 64 rows x 128 k bf16, stride 136
    __shared__ int tok[64];

    const int tid = threadIdx.x;
    const int s   = blockIdx.x;
    const int r0  = blockIdx.y * 128;

    if (tid < 64) tok[tid] = seq[tid * SEQ + s];
    __syncthreads();

    const int w   = tid >> 6;
    const int l   = tid & 63;
    const int l16 = l & 15;
    const int kq  = l >> 4;

    const float* wrow0 = Wih + (size_t)(r0 + 32 * w + l16) * EMBED;
    const float* wrow1 = wrow0 + 16 * EMBED;

    floatx4 acc[4][2];
#pragma unroll
    for (int mt = 0; mt < 4; ++mt)
#pragma unroll
        for (int nt = 0; nt < 2; ++nt)
            acc[mt][nt] = (floatx4){0.f, 0.f, 0.f, 0.f};

    const int arow  = tid >> 2;
    const int apart = tid & 3;
    const float* asrc_base = emb + (size_t)tok[arow] * EMBED + apart * 32;
    unsigned short* adst = Als + arow * 136 + apart * 32;

    for (int kb = 0; kb < EMBED; kb += 128) {
        const float* asrc = asrc_base + kb;
#pragma unroll
        for (int j = 0; j < 4; ++j)
            *(bf16x8*)(adst + j * 8) = cvt8(asrc + j * 8);
        __syncthreads();

#pragma unroll
        for (int kc = 0; kc < 4; ++kc) {
            const int ko = kb + kc * 32 + kq * 8;
            const bf16x8 b0 = cvt8(wrow0 + ko);
            const bf16x8 b1 = cvt8(wrow1 + ko);
#pragma unroll
            for (int mt = 0; mt < 4; ++mt) {
                const bf16x8 af = *(const bf16x8*)(Als + (mt * 16 + l16) * 136 + kc * 32 + kq * 8);
                acc[mt][0] = __builtin_amdgcn_mfma_f32_16x16x32_bf16(af, b0, acc[mt][0], 0, 0, 0);
                acc[mt][1] = __builtin_amdgcn_mfma_f32_16x16x32_bf16(af, b1, acc[mt][1], 0, 0, 0);
            }
        }
        __syncthreads();
    }

    const int rA = r0 + 32 * w + l16;
    const float bv0 = bih[rA] + bhh[rA];
    const float bv1 = bih[rA + 16] + bhh[rA + 16];
    float* gxs = gx + (size_t)s * (R4 * BATCH);
#pragma unroll
    for (int nt = 0; nt < 2; ++nt) {
        const float bv = nt ? bv1 : bv0;
        const int r = rA + 16 * nt;
#pragma unroll
        for (int mt = 0; mt < 4; ++mt) {
            float4 v;
            v.x = acc[mt][nt][0] + bv;
            v.y = acc[mt][nt][1] + bv;
            v.z = acc[mt][nt][2] + bv;
            v.w = acc[mt][nt][3] + bv;
            *(float4*)(gxs + (size_t)r * BATCH + mt * 16 + kq * 4) = v;
        }
    }
}

// ---------------------------------------------------------------------------
// Phase B: persistent LSTM, 256 blocks x 256 thr (cooperative launch for
// co-residency only). Epoch-flag grid barrier (NO atomic RMW):
//   wave0: coalesced nt stores of h (8B) + out (16B) -> fence(release,agent)
//   tid0 : relaxed agent atomic STORE of epoch s+2 to flags[bid] (own line,
//          no serialization) ; all: prefetch gx(s+1) during poll
//   wave0: 64 lanes each poll 4 flags (relaxed agent loads, parallel),
//          __all(min >= epoch) ; s_sleep between iterations
//   sync ; fence(acquire,agent) on every wave
// MFMA reduction split into 2 independent accumulator chains.
// ---------------------------------------------------------------------------
__global__ __launch_bounds__(256) void lstm_mfma(
    const float* __restrict__ gx, const float* __restrict__ Whh,
    unsigned short* __restrict__ h0buf, unsigned short* __restrict__ h1buf,
    unsigned int* flags, float* __restrict__ out)
{
    __shared__ unsigned short Wlds[16 * 1032];  // 16 rows x 1024 bf16, stride 1032
    __shared__ float Slds[16 * 66];             // D staging [m=16][b=64] fp32
    __shared__ __align__(16) unsigned short Hst[64 * 4];  // h stage [b][ul] bf16
    __shared__ __align__(16) float          Ost[64 * 4];  // out stage [b][ul] fp32

    const int tid = threadIdx.x;
    const int w   = tid >> 6;
    const int l   = tid & 63;
    const int l16 = l & 15;
    const int kq  = l >> 4;
    const int u0  = blockIdx.x * 4;

    // one-time: stage this block's 16 W_hh rows to LDS as bf16
    {
        const int m = tid >> 4;       // 0..15 : m = gate*4 + ulocal
        const int p = tid & 15;
        const int gate = m >> 2, ulm = m & 3;
        const float* src = Whh + (size_t)(gate * HID + u0 + ulm) * HID + p * 64;
        unsigned short* dst = Wlds + m * 1032 + p * 64;
#pragma unroll
        for (int j = 0; j < 8; ++j)
            *(bf16x8*)(dst + j * 8) = cvt8(src + j * 8);
    }

    const int ul = w;
    const int b  = l;
    const int u  = u0 + ul;

    float c = 0.f, hval = 0.f;

    // ---- prologue: zero h0 slice, release, arrive(1), prefetch gx(0), wait --
    if (w == 0) {
        uintx2 z; z.x = 0u; z.y = 0u;
        __builtin_nontemporal_store(z, (uintx2*)(h0buf + (size_t)tid * HID + u0));
        __builtin_amdgcn_fence(__ATOMIC_RELEASE, "agent");
    }
    __syncthreads();   // also orders Wlds staging before first use
    if (tid == 0)
        __hip_atomic_store(&flags[blockIdx.x], 1u, __ATOMIC_RELAXED,
                           __HIP_MEMORY_SCOPE_AGENT);

    float gxi = gx[(size_t)(0 * HID + u) * BATCH + b];
    float gxf = gx[(size_t)(1 * HID + u) * BATCH + b];
    float gxg = gx[(size_t)(2 * HID + u) * BATCH + b];
    float gxo = gx[(size_t)(3 * HID + u) * BATCH + b];

    if (w == 0) {
        for (;;) {
            unsigned int f0 = __hip_atomic_load(&flags[l],       __ATOMIC_RELAXED, __HIP_MEMORY_SCOPE_AGENT);
            unsigned int f1 = __hip_atomic_load(&flags[l + 64],  __ATOMIC_RELAXED, __HIP_MEMORY_SCOPE_AGENT);
            unsigned int f2 = __hip_atomic_load(&flags[l + 128], __ATOMIC_RELAXED, __HIP_MEMORY_SCOPE_AGENT);
            unsigned int f3 = __hip_atomic_load(&flags[l + 192], __ATOMIC_RELAXED, __HIP_MEMORY_SCOPE_AGENT);
            unsigned int m01 = f0 < f1 ? f0 : f1;
            unsigned int m23 = f2 < f3 ? f2 : f3;
            unsigned int mn  = m01 < m23 ? m01 : m23;
            if (__all(mn >= 1u)) break;
            __builtin_amdgcn_s_sleep(1);
        }
    }
    __syncthreads();
    __builtin_amdgcn_fence(__ATOMIC_ACQUIRE, "agent");

    const unsigned short* wbase = Wlds + l16 * 1032 + kq * 8;   // A-frag: m=l16

    for (int s = 0; s < SEQ; ++s) {
        const unsigned short* hb = (s & 1) ? h1buf : h0buf;
        unsigned short*       hn = (s & 1) ? h0buf : h1buf;

        // B-frag: n = batch 16w+l16, k contiguous -> 16B loads
        const unsigned short* hbase = hb + (size_t)(16 * w + l16) * HID + kq * 8;

        floatx4 acc0 = (floatx4){0.f, 0.f, 0.f, 0.f};
        floatx4 acc1 = (floatx4){0.f, 0.f, 0.f, 0.f};
#pragma unroll
        for (int kc = 0; kc < 32; kc += 2) {
            const bf16x8 bf0 = *(const bf16x8*)(hbase + kc * 32);
            const bf16x8 af0 = *(const bf16x8*)(wbase + kc * 32);
            const bf16x8 bf1 = *(const bf16x8*)(hbase + (kc + 1) * 32);
            const bf16x8 af1 = *(const bf16x8*)(wbase + (kc + 1) * 32);
            acc0 = __builtin_amdgcn_mfma_f32_16x16x32_bf16(af0, bf0, acc0, 0, 0, 0);
            acc1 = __builtin_amdgcn_mfma_f32_16x16x32_bf16(af1, bf1, acc1, 0, 0, 0);
        }
        const floatx4 acc = acc0 + acc1;

        // D: m = kq*4+reg, n = 16w+l16
#pragma unroll
        for (int r = 0; r < 4; ++r)
            Slds[(kq * 4 + r) * 66 + 16 * w + l16] = acc[r];
        __syncthreads();                       // sync_a

        const float pi = Slds[(0 * 4 + ul) * 66 + b] + gxi;
        const float pf = Slds[(1 * 4 + ul) * 66 + b] + gxf;
        const float pg = Slds[(2 * 4 + ul) * 66 + b] + gxg;
        const float po = Slds[(3 * 4 + ul) * 66 + b] + gxo;

        const float ig = 1.f / (1.f + __expf(-pi));
        const float fg = 1.f / (1.f + __expf(-pf));
        const float gg = 2.f / (1.f + __expf(-2.f * pg)) - 1.f;   // tanh
        const float og = 1.f / (1.f + __expf(-po));
        c = fg * c + ig * gg;
        const float th = 2.f / (1.f + __expf(-2.f * c)) - 1.f;
        hval = og * th;

        Hst[b * 4 + ul] = f2bf(hval);
        Ost[b * 4 + ul] = hval;
        __syncthreads();                       // sync_b

        // wave0: coalesced nt stores of h (8B/row) and out (16B/row), then
        // release so tid0's arrival store is ordered after them.
        if (w == 0) {
            const uintx2  hv = *(const uintx2*)(Hst + tid * 4);
            const floatx4 ov = *(const floatx4*)(Ost + tid * 4);
            __builtin_nontemporal_store(hv, (uintx2*)(hn + (size_t)tid * HID + u0));
            __builtin_nontemporal_store(ov, (floatx4*)(out + ((size_t)tid * SEQ + s) * HID + u0));
            __builtin_amdgcn_fence(__ATOMIC_RELEASE, "agent");
        }
        // arrive: own-flag epoch store, no RMW (sync_b already ordered all
        // waves' reads of hb for this step before this point)
        const unsigned int ep = (unsigned int)(s + 2);
        if (tid == 0)
            __hip_atomic_store(&flags[blockIdx.x], ep, __ATOMIC_RELAXED,
                               __HIP_MEMORY_SCOPE_AGENT);

        // prefetch next step's gx during the poll window
        {
            const int sn = (s + 1 < SEQ) ? s + 1 : s;
            const float* gxs = gx + (size_t)sn * (R4 * BATCH);
            gxi = gxs[(size_t)(0 * HID + u) * BATCH + b];
            gxf = gxs[(size_t)(1 * HID + u) * BATCH + b];
            gxg = gxs[(size_t)(2 * HID + u) * BATCH + b];
            gxo = gxs[(size_t)(3 * HID + u) * BATCH + b];
        }

        // wait: 64 lanes x 4 flags, parallel relaxed agent loads
        if (w == 0) {
            for (;;) {
                unsigned int f0 = __hip_atomic_load(&flags[l],       __ATOMIC_RELAXED, __HIP_MEMORY_SCOPE_AGENT);
                unsigned int f1 = __hip_atomic_load(&flags[l + 64],  __ATOMIC_RELAXED, __HIP_MEMORY_SCOPE_AGENT);
                unsigned int f2 = __hip_atomic_load(&flags[l + 128], __ATOMIC_RELAXED, __HIP_MEMORY_SCOPE_AGENT);
                unsigned int f3 = __hip_atomic_load(&flags[l + 192], __ATOMIC_RELAXED, __HIP_MEMORY_SCOPE_AGENT);
                unsigned int m01 = f0 < f1 ? f0 : f1;
                unsigned int m23 = f2 < f3 ? f2 : f3;
                unsigned int mn  = m01 < m23 ? m01 : m23;
                if (__all(mn >= ep)) break;
                __builtin_amdgcn_s_sleep(1);
            }
        }
        __syncthreads();                       // holds all waves on poll
        __builtin_amdgcn_fence(__ATOMIC_ACQUIRE, "agent");
    }

    float* hlast = out + (size_t)BATCH * SEQ * HID;
    float* clast = hlast + (size_t)BATCH * HID;
    hlast[(size_t)b * HID + u] = hval;
    clast[(size_t)b * HID + u] = c;
}

// ---------------------------------------------------------------------------
extern "C" void kernel_launch(void* const* d_in, const int* in_sizes, int n_in,
                              void* d_out, int out_size, void* d_ws, size_t ws_size,
                              hipStream_t stream)
{
    const float* emb = (const float*)d_in[0];
    const float* Wih = (const float*)d_in[1];
    const float* Whh = (const float*)d_in[2];
    const float* bih = (const float*)d_in[3];
    const float* bhh = (const float*)d_in[4];
    const int*   seq = (const int*)d_in[5];
    float* out = (float*)d_out;

    // ws: gx fp32 [512][4096][64] + 2 bf16 h buffers + 256 barrier flags
    float* gx = (float*)d_ws;
    unsigned short* h0 = (unsigned short*)(gx + (size_t)SEQ * R4 * BATCH);
    unsigned short* h1 = h0 + (size_t)BATCH * HID;

    const size_t needed = (size_t)SEQ * R4 * BATCH * 4 + (size_t)2 * BATCH * HID * 2;
    unsigned int* flags;
    if (ws_size >= needed + NBLK * 4) {
        flags = (unsigned int*)(h1 + (size_t)BATCH * HID);
    } else {
        // fallback: last 256 floats of c_last. Safe: a block only overwrites
        // them after observing ALL blocks at the final epoch, i.e. after every
        // h store in the program is already released; any spurious poll pass
        // caused by the overwrite can no longer order anything incorrectly.
        flags = (unsigned int*)((float*)d_out + (size_t)BATCH * SEQ * HID
                                + 2 * (size_t)BATCH * HID - NBLK);
    }

    dim3 gA(512, 32);
    gates_x_mfma<<<gA, 256, 0, stream>>>(emb, Wih, bih, bhh, seq, gx, flags);

    void* args[] = { (void*)&gx, (void*)&Whh, (void*)&h0, (void*)&h1,
                     (void*)&flags, (void*)&out };
    (void)hipLaunchCooperativeKernel((void*)lstm_mfma, dim3(256), dim3(256), args, 0, stream);
}

// Round 4
// 8018.093 us; speedup vs baseline: 2.5881x; 1.7270x over previous
//
#include <hip/hip_runtime.h>

#define VOCAB 32000
#define EMBED 1024
#define HID   1024
#define BATCH 64
#define SEQ   512
#define R4    4096   // 4*HID gate rows (i,f,g,o)
#define NBLK  256    // phase-B grid size

typedef float floatx4 __attribute__((ext_vector_type(4)));
typedef unsigned int uintx2 __attribute__((ext_vector_type(2)));
typedef short bf16x8  __attribute__((ext_vector_type(8)));   // 8 bf16 = 4 VGPRs
typedef unsigned long long u64;

// fp32 -> bf16 round-to-nearest-even
static __device__ __forceinline__ unsigned short f2bf(float x) {
    unsigned int u = __float_as_uint(x);
    u = (u + 0x7FFFu + ((u >> 16) & 1u)) >> 16;
    return (unsigned short)u;
}

// load 8 contiguous fp32, convert to bf16x8 fragment
static __device__ __forceinline__ bf16x8 cvt8(const float* p) {
    float4 a = ((const float4*)p)[0];
    float4 b = ((const float4*)p)[1];
    bf16x8 r;
    r[0] = (short)f2bf(a.x); r[1] = (short)f2bf(a.y);
    r[2] = (short)f2bf(a.z); r[3] = (short)f2bf(a.w);
    r[4] = (short)f2bf(b.x); r[5] = (short)f2bf(b.y);
    r[6] = (short)f2bf(b.z); r[7] = (short)f2bf(b.w);
    return r;
}

// ---------------------------------------------------------------------------
// Phase A: gx[s][r][b] = emb[seq[b][s]] . W_ih[r] + b_ih[r] + b_hh[r]  (fp32)
// (unchanged; zeroes the phase-B barrier flag array each replay)
// ---------------------------------------------------------------------------
__global__ __launch_bounds__(256) void gates_x_mfma(
    const float* __restrict__ emb, const float* __restrict__ Wih,
    const float* __restrict__ bih, const float* __restrict__ bhh,
    const int* __restrict__ seq, float* __restrict__ gx,
    unsigned int* flags)
{
    if (blockIdx.x == 0 && blockIdx.y == 0) flags[threadIdx.x] = 0u;

    __shared__ unsigned short Als[64 * 136];   // 64 rows x 128 k bf16, stride 136
    __shared__ int tok[64];

    const int tid = threadIdx.x;
    const int s   = blockIdx.x;
    const int r0  = blockIdx.y * 128;

    if (tid < 64) tok[tid] = seq[tid * SEQ + s];
    __syncthreads();

    const int w   = tid >> 6;
    const int l   = tid & 63;
    const int l16 = l & 15;
    const int kq  = l >> 4;

    const float* wrow0 = Wih + (size_t)(r0 + 32 * w + l16) * EMBED;
    const float* wrow1 = wrow0 + 16 * EMBED;

    floatx4 acc[4][2];
#pragma unroll
    for (int mt = 0; mt < 4; ++mt)
#pragma unroll
        for (int nt = 0; nt < 2; ++nt)
            acc[mt][nt] = (floatx4){0.f, 0.f, 0.f, 0.f};

    const int arow  = tid >> 2;
    const int apart = tid & 3;
    const float* asrc_base = emb + (size_t)tok[arow] * EMBED + apart * 32;
    unsigned short* adst = Als + arow * 136 + apart * 32;

    for (int kb = 0; kb < EMBED; kb += 128) {
        const float* asrc = asrc_base + kb;
#pragma unroll
        for (int j = 0; j < 4; ++j)
            *(bf16x8*)(adst + j * 8) = cvt8(asrc + j * 8);
        __syncthreads();

#pragma unroll
        for (int kc = 0; kc < 4; ++kc) {
            const int ko = kb + kc * 32 + kq * 8;
            const bf16x8 b0 = cvt8(wrow0 + ko);
            const bf16x8 b1 = cvt8(wrow1 + ko);
#pragma unroll
            for (int mt = 0; mt < 4; ++mt) {
                const bf16x8 af = *(const bf16x8*)(Als + (mt * 16 + l16) * 136 + kc * 32 + kq * 8);
                acc[mt][0] = __builtin_amdgcn_mfma_f32_16x16x32_bf16(af, b0, acc[mt][0], 0, 0, 0);
                acc[mt][1] = __builtin_amdgcn_mfma_f32_16x16x32_bf16(af, b1, acc[mt][1], 0, 0, 0);
            }
        }
        __syncthreads();
    }

    const int rA = r0 + 32 * w + l16;
    const float bv0 = bih[rA] + bhh[rA];
    const float bv1 = bih[rA + 16] + bhh[rA + 16];
    float* gxs = gx + (size_t)s * (R4 * BATCH);
#pragma unroll
    for (int nt = 0; nt < 2; ++nt) {
        const float bv = nt ? bv1 : bv0;
        const int r = rA + 16 * nt;
#pragma unroll
        for (int mt = 0; mt < 4; ++mt) {
            float4 v;
            v.x = acc[mt][nt][0] + bv;
            v.y = acc[mt][nt][1] + bv;
            v.z = acc[mt][nt][2] + bv;
            v.w = acc[mt][nt][3] + bv;
            *(float4*)(gxs + (size_t)r * BATCH + mt * 16 + kq * 4) = v;
        }
    }
}

// ---------------------------------------------------------------------------
// Phase B: persistent LSTM, 256 blocks x 256 thr. FENCE-FREE epoch barrier:
// all cross-block data (h, flags) moves via agent-scope relaxed atomic 8-B
// ops, which bypass L1/L2 and are served coherently at the MALL. Release
// ordering = raw s_waitcnt vmcnt(0) (h acks at MALL) before the flag store.
// No buffer_wbl2 / buffer_inv anywhere in the loop.
// ---------------------------------------------------------------------------
__global__ __launch_bounds__(256) void lstm_mfma(
    const float* __restrict__ gx, const float* __restrict__ Whh,
    unsigned short* __restrict__ h0buf, unsigned short* __restrict__ h1buf,
    unsigned int* flags, float* __restrict__ out)
{
    __shared__ unsigned short Wlds[16 * 1032];  // 16 rows x 1024 bf16, stride 1032
    __shared__ float Slds[16 * 66];             // D staging [m=16][b=64] fp32
    __shared__ __align__(16) unsigned short Hst[64 * 4];  // h stage [b][ul] bf16
    __shared__ __align__(16) float          Ost[64 * 4];  // out stage [b][ul] fp32

    const int tid = threadIdx.x;
    const int w   = tid >> 6;
    const int l   = tid & 63;
    const int l16 = l & 15;
    const int kq  = l >> 4;
    const int u0  = blockIdx.x * 4;

    // one-time: stage this block's 16 W_hh rows to LDS as bf16
    {
        const int m = tid >> 4;       // 0..15 : m = gate*4 + ulocal
        const int p = tid & 15;
        const int gate = m >> 2, ulm = m & 3;
        const float* src = Whh + (size_t)(gate * HID + u0 + ulm) * HID + p * 64;
        unsigned short* dst = Wlds + m * 1032 + p * 64;
#pragma unroll
        for (int j = 0; j < 8; ++j)
            *(bf16x8*)(dst + j * 8) = cvt8(src + j * 8);
    }

    const int ul = w;
    const int b  = l;
    const int u  = u0 + ul;

    float c = 0.f, hval = 0.f;

    // ---- prologue: zero h0 slice via MALL, arrive(1), prefetch gx(0), wait --
    if (w == 0) {
        __hip_atomic_store((u64*)(h0buf + (size_t)tid * HID + u0), 0ull,
                           __ATOMIC_RELAXED, __HIP_MEMORY_SCOPE_AGENT);
        asm volatile("s_waitcnt vmcnt(0)" ::: "memory");
    }
    __syncthreads();   // also orders Wlds staging before first use
    if (tid == 0)
        __hip_atomic_store(&flags[blockIdx.x], 1u, __ATOMIC_RELAXED,
                           __HIP_MEMORY_SCOPE_AGENT);

    float gxi = gx[(size_t)(0 * HID + u) * BATCH + b];
    float gxf = gx[(size_t)(1 * HID + u) * BATCH + b];
    float gxg = gx[(size_t)(2 * HID + u) * BATCH + b];
    float gxo = gx[(size_t)(3 * HID + u) * BATCH + b];

    if (w == 0) {
        for (;;) {
            unsigned int f0 = __hip_atomic_load(&flags[l],       __ATOMIC_RELAXED, __HIP_MEMORY_SCOPE_AGENT);
            unsigned int f1 = __hip_atomic_load(&flags[l + 64],  __ATOMIC_RELAXED, __HIP_MEMORY_SCOPE_AGENT);
            unsigned int f2 = __hip_atomic_load(&flags[l + 128], __ATOMIC_RELAXED, __HIP_MEMORY_SCOPE_AGENT);
            unsigned int f3 = __hip_atomic_load(&flags[l + 192], __ATOMIC_RELAXED, __HIP_MEMORY_SCOPE_AGENT);
            unsigned int m01 = f0 < f1 ? f0 : f1;
            unsigned int m23 = f2 < f3 ? f2 : f3;
            unsigned int mn  = m01 < m23 ? m01 : m23;
            if (__all(mn >= 1u)) break;
            __builtin_amdgcn_s_sleep(1);
        }
    }
    __syncthreads();
    asm volatile("" ::: "memory");   // keep h loads below the poll

    const unsigned short* wbase = Wlds + l16 * 1032 + kq * 8;   // A-frag: m=l16

    for (int s = 0; s < SEQ; ++s) {
        const unsigned short* hb = (s & 1) ? h1buf : h0buf;
        unsigned short*       hn = (s & 1) ? h0buf : h1buf;

        // B-frag: n = batch 16w+l16, k contiguous; 2x 8-B agent atomic loads
        // per fragment (sc1 -> served at MALL, always coherent, no fences)
        const unsigned short* hbase = hb + (size_t)(16 * w + l16) * HID + kq * 8;

        floatx4 acc0 = (floatx4){0.f, 0.f, 0.f, 0.f};
        floatx4 acc1 = (floatx4){0.f, 0.f, 0.f, 0.f};
#pragma unroll
        for (int kc = 0; kc < 32; kc += 2) {
            union { u64 q[2]; bf16x8 v; } fb0, fb1;
            fb0.q[0] = __hip_atomic_load((u64*)(hbase + kc * 32),           __ATOMIC_RELAXED, __HIP_MEMORY_SCOPE_AGENT);
            fb0.q[1] = __hip_atomic_load((u64*)(hbase + kc * 32 + 4),       __ATOMIC_RELAXED, __HIP_MEMORY_SCOPE_AGENT);
            fb1.q[0] = __hip_atomic_load((u64*)(hbase + (kc + 1) * 32),     __ATOMIC_RELAXED, __HIP_MEMORY_SCOPE_AGENT);
            fb1.q[1] = __hip_atomic_load((u64*)(hbase + (kc + 1) * 32 + 4), __ATOMIC_RELAXED, __HIP_MEMORY_SCOPE_AGENT);
            const bf16x8 af0 = *(const bf16x8*)(wbase + kc * 32);
            const bf16x8 af1 = *(const bf16x8*)(wbase + (kc + 1) * 32);
            acc0 = __builtin_amdgcn_mfma_f32_16x16x32_bf16(af0, fb0.v, acc0, 0, 0, 0);
            acc1 = __builtin_amdgcn_mfma_f32_16x16x32_bf16(af1, fb1.v, acc1, 0, 0, 0);
        }
        const floatx4 acc = acc0 + acc1;

        // D: m = kq*4+reg, n = 16w+l16
#pragma unroll
        for (int r = 0; r < 4; ++r)
            Slds[(kq * 4 + r) * 66 + 16 * w + l16] = acc[r];
        __syncthreads();                       // sync_a

        const float pi = Slds[(0 * 4 + ul) * 66 + b] + gxi;
        const float pf = Slds[(1 * 4 + ul) * 66 + b] + gxf;
        const float pg = Slds[(2 * 4 + ul) * 66 + b] + gxg;
        const float po = Slds[(3 * 4 + ul) * 66 + b] + gxo;

        const float ig = 1.f / (1.f + __expf(-pi));
        const float fg = 1.f / (1.f + __expf(-pf));
        const float gg = 2.f / (1.f + __expf(-2.f * pg)) - 1.f;   // tanh
        const float og = 1.f / (1.f + __expf(-po));
        c = fg * c + ig * gg;
        const float th = 2.f / (1.f + __expf(-2.f * c)) - 1.f;
        hval = og * th;

        Hst[b * 4 + ul] = f2bf(hval);
        Ost[b * 4 + ul] = hval;
        __syncthreads();                       // sync_b

        // wave0: out as plain cached store (fast L2 ack, nobody reads it
        // cross-block); h as 8-B agent atomic store (lands at MALL); then
        // raw vmcnt(0) so tid0's flag store is ordered after both.
        if (w == 0) {
            union { uintx2 v; u64 q; } hv;
            hv.v = *(const uintx2*)(Hst + tid * 4);
            const floatx4 ov = *(const floatx4*)(Ost + tid * 4);
            *(floatx4*)(out + ((size_t)tid * SEQ + s) * HID + u0) = ov;
            __hip_atomic_store((u64*)(hn + (size_t)tid * HID + u0), hv.q,
                               __ATOMIC_RELAXED, __HIP_MEMORY_SCOPE_AGENT);
            asm volatile("s_waitcnt vmcnt(0)" ::: "memory");
        }
        // arrive: own-flag epoch store (sync_b already ordered all waves'
        // reads of hb for this step before this point)
        const unsigned int ep = (unsigned int)(s + 2);
        if (tid == 0)
            __hip_atomic_store(&flags[blockIdx.x], ep, __ATOMIC_RELAXED,
                               __HIP_MEMORY_SCOPE_AGENT);

        // prefetch next step's gx during the poll window (plain cached loads)
        {
            const int sn = (s + 1 < SEQ) ? s + 1 : s;
            const float* gxs = gx + (size_t)sn * (R4 * BATCH);
            gxi = gxs[(size_t)(0 * HID + u) * BATCH + b];
            gxf = gxs[(size_t)(1 * HID + u) * BATCH + b];
            gxg = gxs[(size_t)(2 * HID + u) * BATCH + b];
            gxo = gxs[(size_t)(3 * HID + u) * BATCH + b];
        }

        // wait: 64 lanes x 4 flags, parallel relaxed agent loads
        if (w == 0) {
            for (;;) {
                unsigned int f0 = __hip_atomic_load(&flags[l],       __ATOMIC_RELAXED, __HIP_MEMORY_SCOPE_AGENT);
                unsigned int f1 = __hip_atomic_load(&flags[l + 64],  __ATOMIC_RELAXED, __HIP_MEMORY_SCOPE_AGENT);
                unsigned int f2 = __hip_atomic_load(&flags[l + 128], __ATOMIC_RELAXED, __HIP_MEMORY_SCOPE_AGENT);
                unsigned int f3 = __hip_atomic_load(&flags[l + 192], __ATOMIC_RELAXED, __HIP_MEMORY_SCOPE_AGENT);
                unsigned int m01 = f0 < f1 ? f0 : f1;
                unsigned int m23 = f2 < f3 ? f2 : f3;
                unsigned int mn  = m01 < m23 ? m01 : m23;
                if (__all(mn >= ep)) break;
                __builtin_amdgcn_s_sleep(1);
            }
        }
        __syncthreads();                       // holds all waves on poll
        asm volatile("" ::: "memory");         // keep next h loads below poll
    }

    float* hlast = out + (size_t)BATCH * SEQ * HID;
    float* clast = hlast + (size_t)BATCH * HID;
    hlast[(size_t)b * HID + u] = hval;
    clast[(size_t)b * HID + u] = c;
}

// ---------------------------------------------------------------------------
extern "C" void kernel_launch(void* const* d_in, const int* in_sizes, int n_in,
                              void* d_out, int out_size, void* d_ws, size_t ws_size,
                              hipStream_t stream)
{
    const float* emb = (const float*)d_in[0];
    const float* Wih = (const float*)d_in[1];
    const float* Whh = (const float*)d_in[2];
    const float* bih = (const float*)d_in[3];
    const float* bhh = (const float*)d_in[4];
    const int*   seq = (const int*)d_in[5];
    float* out = (float*)d_out;

    // ws: gx fp32 [512][4096][64] + 2 bf16 h buffers + 256 barrier flags
    float* gx = (float*)d_ws;
    unsigned short* h0 = (unsigned short*)(gx + (size_t)SEQ * R4 * BATCH);
    unsigned short* h1 = h0 + (size_t)BATCH * HID;

    const size_t needed = (size_t)SEQ * R4 * BATCH * 4 + (size_t)2 * BATCH * HID * 2;
    unsigned int* flags;
    if (ws_size >= needed + NBLK * 4) {
        flags = (unsigned int*)(h1 + (size_t)BATCH * HID);
    } else {
        // fallback: last 256 floats of c_last. Safe: a block only overwrites
        // them after observing ALL blocks at the final epoch.
        flags = (unsigned int*)((float*)d_out + (size_t)BATCH * SEQ * HID
                                + 2 * (size_t)BATCH * HID - NBLK);
    }

    dim3 gA(512, 32);
    gates_x_mfma<<<gA, 256, 0, stream>>>(emb, Wih, bih, bhh, seq, gx, flags);

    void* args[] = { (void*)&gx, (void*)&Whh, (void*)&h0, (void*)&h1,
                     (void*)&flags, (void*)&out };
    (void)hipLaunchCooperativeKernel((void*)lstm_mfma, dim3(256), dim3(256), args, 0, stream);
}

// Round 6
// 7893.132 us; speedup vs baseline: 2.6291x; 1.0158x over previous
//
#include <hip/hip_runtime.h>

#define VOCAB 32000
#define EMBED 1024
#define HID   1024
#define BATCH 64
#define SEQ   512
#define R4    4096   // 4*HID gate rows (i,f,g,o)
#define NBLK  256    // flag array size (phase A zeroes this many)
#define PBLK  64     // phase-B grid size
#define UPB   16     // units per phase-B block

typedef float floatx4 __attribute__((ext_vector_type(4)));
typedef unsigned int uintx2 __attribute__((ext_vector_type(2)));
typedef short bf16x8  __attribute__((ext_vector_type(8)));   // 8 bf16 = 4 VGPRs
typedef unsigned long long u64;

// fp32 -> bf16 round-to-nearest-even
static __device__ __forceinline__ unsigned short f2bf(float x) {
    unsigned int u = __float_as_uint(x);
    u = (u + 0x7FFFu + ((u >> 16) & 1u)) >> 16;
    return (unsigned short)u;
}

// load 8 contiguous fp32, convert to bf16x8 fragment
static __device__ __forceinline__ bf16x8 cvt8(const float* p) {
    float4 a = ((const float4*)p)[0];
    float4 b = ((const float4*)p)[1];
    bf16x8 r;
    r[0] = (short)f2bf(a.x); r[1] = (short)f2bf(a.y);
    r[2] = (short)f2bf(a.z); r[3] = (short)f2bf(a.w);
    r[4] = (short)f2bf(b.x); r[5] = (short)f2bf(b.y);
    r[6] = (short)f2bf(b.z); r[7] = (short)f2bf(b.w);
    return r;
}

// ---------------------------------------------------------------------------
// Phase A: gx[s][r][b] = emb[seq[b][s]] . W_ih[r] + b_ih[r] + b_hh[r]  (fp32)
// (unchanged; zeroes the phase-B barrier flag array each replay)
// ---------------------------------------------------------------------------
__global__ __launch_bounds__(256) void gates_x_mfma(
    const float* __restrict__ emb, const float* __restrict__ Wih,
    const float* __restrict__ bih, const float* __restrict__ bhh,
    const int* __restrict__ seq, float* __restrict__ gx,
    unsigned int* flags)
{
    if (blockIdx.x == 0 && blockIdx.y == 0) flags[threadIdx.x] = 0u;

    __shared__ unsigned short Als[64 * 136];   // 64 rows x 128 k bf16, stride 136
    __shared__ int tok[64];

    const int tid = threadIdx.x;
    const int s   = blockIdx.x;
    const int r0  = blockIdx.y * 128;

    if (tid < 64) tok[tid] = seq[tid * SEQ + s];
    __syncthreads();

    const int w   = tid >> 6;
    const int l   = tid & 63;
    const int l16 = l & 15;
    const int kq  = l >> 4;

    const float* wrow0 = Wih + (size_t)(r0 + 32 * w + l16) * EMBED;
    const float* wrow1 = wrow0 + 16 * EMBED;

    floatx4 acc[4][2];
#pragma unroll
    for (int mt = 0; mt < 4; ++mt)
#pragma unroll
        for (int nt = 0; nt < 2; ++nt)
            acc[mt][nt] = (floatx4){0.f, 0.f, 0.f, 0.f};

    const int arow  = tid >> 2;
    const int apart = tid & 3;
    const float* asrc_base = emb + (size_t)tok[arow] * EMBED + apart * 32;
    unsigned short* adst = Als + arow * 136 + apart * 32;

    for (int kb = 0; kb < EMBED; kb += 128) {
        const float* asrc = asrc_base + kb;
#pragma unroll
        for (int j = 0; j < 4; ++j)
            *(bf16x8*)(adst + j * 8) = cvt8(asrc + j * 8);
        __syncthreads();

#pragma unroll
        for (int kc = 0; kc < 4; ++kc) {
            const int ko = kb + kc * 32 + kq * 8;
            const bf16x8 b0 = cvt8(wrow0 + ko);
            const bf16x8 b1 = cvt8(wrow1 + ko);
#pragma unroll
            for (int mt = 0; mt < 4; ++mt) {
                const bf16x8 af = *(const bf16x8*)(Als + (mt * 16 + l16) * 136 + kc * 32 + kq * 8);
                acc[mt][0] = __builtin_amdgcn_mfma_f32_16x16x32_bf16(af, b0, acc[mt][0], 0, 0, 0);
                acc[mt][1] = __builtin_amdgcn_mfma_f32_16x16x32_bf16(af, b1, acc[mt][1], 0, 0, 0);
            }
        }
        __syncthreads();
    }

    const int rA = r0 + 32 * w + l16;
    const float bv0 = bih[rA] + bhh[rA];
    const float bv1 = bih[rA + 16] + bhh[rA + 16];
    float* gxs = gx + (size_t)s * (R4 * BATCH);
#pragma unroll
    for (int nt = 0; nt < 2; ++nt) {
        const float bv = nt ? bv1 : bv0;
        const int r = rA + 16 * nt;
#pragma unroll
        for (int mt = 0; mt < 4; ++mt) {
            float4 v;
            v.x = acc[mt][nt][0] + bv;
            v.y = acc[mt][nt][1] + bv;
            v.z = acc[mt][nt][2] + bv;
            v.w = acc[mt][nt][3] + bv;
            *(float4*)(gxs + (size_t)r * BATCH + mt * 16 + kq * 4) = v;
        }
    }
}

// ---------------------------------------------------------------------------
// Phase B: persistent LSTM, 64 blocks x 1024 thr (16 units/block, 16 waves:
// wave w -> gate mi=w&3, batch-group ni=w>>2). W_hh frags live in REGISTERS
// (128 VGPR/lane, loaded once). Per step: block stages the full h (128 KB)
// into LDS cooperatively via 8-B agent-atomic loads (MALL-coherent, no
// fences) -> 4x less MALL traffic than 256 blocks. MFMA B-frags read from
// LDS. Slds/Hst/Ost alias the h LDS region (dead after MFMA; guarded by
// syncthreads on both sides). Fence-free epoch barrier, 64 flags.
// ---------------------------------------------------------------------------
__global__ __launch_bounds__(1024) void lstm_mfma(
    const float* __restrict__ gx, const float* __restrict__ Whh,
    unsigned short* __restrict__ h0buf, unsigned short* __restrict__ h1buf,
    unsigned int* flags, float* __restrict__ out)
{
    __shared__ __align__(16) unsigned short smem[64 * 1032];   // 132,096 B
    unsigned short* hls = smem;                        // h stage [b][1032] bf16
    float*          Slds = (float*)smem;               // 64 x 66 fp32 (aliases h)
    unsigned short* Hst  = smem + (16896 / 2);         // [b][16] bf16 (aliases h)
    float*          Ost  = (float*)(smem + (18944 / 2)); // [b][16] fp32 (aliases h)

    const int tid = threadIdx.x;          // 0..1023
    const int w   = tid >> 6;             // 0..15
    const int l   = tid & 63;
    const int l16 = l & 15;
    const int kq  = l >> 4;
    const int mi  = w & 3;                // gate index (m-tile)
    const int ni  = w >> 2;               // batch group (n-tile)
    const int u0  = blockIdx.x * UPB;

    // one-time: this wave's W_hh fragments -> registers.
    // m-local = unit_local = l16; global row = gate*HID + (u0 + l16)
    bf16x8 wfrag[32];
    {
        const float* src = Whh + (size_t)(mi * HID + u0 + l16) * HID + kq * 8;
#pragma unroll
        for (int kc = 0; kc < 32; ++kc)
            wfrag[kc] = cvt8(src + kc * 32);
    }

    const int ul = w;     // elementwise: unit-local 0..15
    const int b  = l;     // elementwise: batch 0..63
    const int u  = u0 + ul;

    float c = 0.f, hval = 0.f;

    // ---- prologue: zero h0 via MALL, arrive(1), prefetch gx(0), wait -------
    {
        u64* h0q = (u64*)h0buf;
#pragma unroll
        for (int j = 0; j < 16; ++j)
            __hip_atomic_store(h0q + j * 1024 + tid, 0ull,
                               __ATOMIC_RELAXED, __HIP_MEMORY_SCOPE_AGENT);
        asm volatile("s_waitcnt vmcnt(0)" ::: "memory");
    }
    __syncthreads();
    if (tid == 0)
        __hip_atomic_store(&flags[blockIdx.x], 1u, __ATOMIC_RELAXED,
                           __HIP_MEMORY_SCOPE_AGENT);

    float gxi = gx[(size_t)(0 * HID + u) * BATCH + b];
    float gxf = gx[(size_t)(1 * HID + u) * BATCH + b];
    float gxg = gx[(size_t)(2 * HID + u) * BATCH + b];
    float gxo = gx[(size_t)(3 * HID + u) * BATCH + b];

    if (w == 0) {   // 64 lanes, 1 flag each
        for (;;) {
            unsigned int f = __hip_atomic_load(&flags[l], __ATOMIC_RELAXED,
                                               __HIP_MEMORY_SCOPE_AGENT);
            if (__all(f >= 1u)) break;
            __builtin_amdgcn_s_sleep(1);
        }
    }
    __syncthreads();
    asm volatile("" ::: "memory");

    for (int s = 0; s < SEQ; ++s) {
        const unsigned short* hb = (s & 1) ? h1buf : h0buf;
        unsigned short*       hn = (s & 1) ? h0buf : h1buf;

        // ---- stage full h (128 KB) -> LDS: 16 x 8-B MALL loads per thread --
        {
            const u64* hq = (const u64*)hb;
            u64 tmp[16];
#pragma unroll
            for (int j = 0; j < 16; ++j)
                tmp[j] = __hip_atomic_load(hq + j * 1024 + tid,
                                           __ATOMIC_RELAXED, __HIP_MEMORY_SCOPE_AGENT);
#pragma unroll
            for (int j = 0; j < 16; ++j) {
                const int cc = j * 1024 + tid;          // u64 chunk index
                *(u64*)(hls + (cc >> 8) * 1032 + (cc & 255) * 4) = tmp[j];
            }
        }
        __syncthreads();

        // ---- MFMA: A = wfrag (regs), B = h from LDS ------------------------
        const unsigned short* hbase = hls + (ni * 16 + l16) * 1032 + kq * 8;
        floatx4 acc0 = (floatx4){0.f, 0.f, 0.f, 0.f};
        floatx4 acc1 = (floatx4){0.f, 0.f, 0.f, 0.f};
#pragma unroll
        for (int kc = 0; kc < 32; kc += 2) {
            const bf16x8 bf0 = *(const bf16x8*)(hbase + kc * 32);
            const bf16x8 bf1 = *(const bf16x8*)(hbase + (kc + 1) * 32);
            acc0 = __builtin_amdgcn_mfma_f32_16x16x32_bf16(wfrag[kc],     bf0, acc0, 0, 0, 0);
            acc1 = __builtin_amdgcn_mfma_f32_16x16x32_bf16(wfrag[kc + 1], bf1, acc1, 0, 0, 0);
        }
        const floatx4 acc = acc0 + acc1;
        __syncthreads();   // all waves done reading h -> safe to alias LDS

        // D: m = mi*16 + kq*4 + r (= gate*16 + unit_local), n = ni*16 + l16
#pragma unroll
        for (int r = 0; r < 4; ++r)
            Slds[(mi * 16 + kq * 4 + r) * 66 + ni * 16 + l16] = acc[r];
        __syncthreads();

        // ---- elementwise: thread (ul, b) owns (unit u0+ul, batch b) --------
        const float pi = Slds[(0 * 16 + ul) * 66 + b] + gxi;
        const float pf = Slds[(1 * 16 + ul) * 66 + b] + gxf;
        const float pg = Slds[(2 * 16 + ul) * 66 + b] + gxg;
        const float po = Slds[(3 * 16 + ul) * 66 + b] + gxo;

        const float ig = 1.f / (1.f + __expf(-pi));
        const float fg = 1.f / (1.f + __expf(-pf));
        const float gg = 2.f / (1.f + __expf(-2.f * pg)) - 1.f;   // tanh
        const float og = 1.f / (1.f + __expf(-po));
        c = fg * c + ig * gg;
        const float th = 2.f / (1.f + __expf(-2.f * c)) - 1.f;
        hval = og * th;

        Hst[b * UPB + ul] = f2bf(hval);
        Ost[b * UPB + ul] = hval;
        __syncthreads();

        // ---- waves 0-3: coalesced stores; h via MALL atomics ---------------
        if (w < 4) {
            const int bb = tid >> 2, part = tid & 3;
            union { uintx2 v; u64 q; } hv;
            hv.v = *(const uintx2*)(Hst + bb * UPB + part * 4);
            const floatx4 ov = *(const floatx4*)(Ost + bb * UPB + part * 4);
            *(floatx4*)(out + ((size_t)bb * SEQ + s) * HID + u0 + part * 4) = ov;
            __hip_atomic_store((u64*)(hn + (size_t)bb * HID + u0 + part * 4), hv.q,
                               __ATOMIC_RELAXED, __HIP_MEMORY_SCOPE_AGENT);
            asm volatile("s_waitcnt vmcnt(0)" ::: "memory");
        }
        __syncthreads();   // order waves 0-3's acked stores before flag store
        const unsigned int ep = (unsigned int)(s + 2);
        if (tid == 0)
            __hip_atomic_store(&flags[blockIdx.x], ep, __ATOMIC_RELAXED,
                               __HIP_MEMORY_SCOPE_AGENT);

        // prefetch next step's gx during the poll window
        {
            const int sn = (s + 1 < SEQ) ? s + 1 : s;
            const float* gxs = gx + (size_t)sn * (R4 * BATCH);
            gxi = gxs[(size_t)(0 * HID + u) * BATCH + b];
            gxf = gxs[(size_t)(1 * HID + u) * BATCH + b];
            gxg = gxs[(size_t)(2 * HID + u) * BATCH + b];
            gxo = gxs[(size_t)(3 * HID + u) * BATCH + b];
        }

        if (w == 0) {
            for (;;) {
                unsigned int f = __hip_atomic_load(&flags[l], __ATOMIC_RELAXED,
                                                   __HIP_MEMORY_SCOPE_AGENT);
                if (__all(f >= ep)) break;
                __builtin_amdgcn_s_sleep(1);
            }
        }
        __syncthreads();
        asm volatile("" ::: "memory");
    }

    float* hlast = out + (size_t)BATCH * SEQ * HID;
    float* clast = hlast + (size_t)BATCH * HID;
    hlast[(size_t)b * HID + u] = hval;
    clast[(size_t)b * HID + u] = c;
}

// ---------------------------------------------------------------------------
extern "C" void kernel_launch(void* const* d_in, const int* in_sizes, int n_in,
                              void* d_out, int out_size, void* d_ws, size_t ws_size,
                              hipStream_t stream)
{
    const float* emb = (const float*)d_in[0];
    const float* Wih = (const float*)d_in[1];
    const float* Whh = (const float*)d_in[2];
    const float* bih = (const float*)d_in[3];
    const float* bhh = (const float*)d_in[4];
    const int*   seq = (const int*)d_in[5];
    float* out = (float*)d_out;

    // ws: gx fp32 [512][4096][64] + 2 bf16 h buffers + barrier flags
    float* gx = (float*)d_ws;
    unsigned short* h0 = (unsigned short*)(gx + (size_t)SEQ * R4 * BATCH);
    unsigned short* h1 = h0 + (size_t)BATCH * HID;

    const size_t needed = (size_t)SEQ * R4 * BATCH * 4 + (size_t)2 * BATCH * HID * 2;
    unsigned int* flags;
    if (ws_size >= needed + NBLK * 4) {
        flags = (unsigned int*)(h1 + (size_t)BATCH * HID);
    } else {
        // fallback: last NBLK floats of c_last. Safe: a block only overwrites
        // them after observing ALL blocks at the final epoch.
        flags = (unsigned int*)((float*)d_out + (size_t)BATCH * SEQ * HID
                                + 2 * (size_t)BATCH * HID - NBLK);
    }

    dim3 gA(512, 32);
    gates_x_mfma<<<gA, 256, 0, stream>>>(emb, Wih, bih, bhh, seq, gx, flags);

    void* args[] = { (void*)&gx, (void*)&Whh, (void*)&h0, (void*)&h1,
                     (void*)&flags, (void*)&out };
    hipError_t lerr = hipLaunchCooperativeKernel((void*)lstm_mfma, dim3(PBLK),
                                                 dim3(1024), args, 0, stream);
    if (lerr != hipSuccess) {
        // 64 blocks x 1 block/CU on 256 CUs: co-resident by construction even
        // under a plain launch; the epoch barrier needs only co-residency.
        lstm_mfma<<<dim3(PBLK), dim3(1024), 0, stream>>>(gx, Whh, h0, h1, flags, out);
    }
}